// Round 1
// baseline (2055.310 us; speedup 1.0000x reference)
//
#include <hip/hip_runtime.h>

// ---------------- CSR build ----------------
__global__ __launch_bounds__(256) void hist_kernel(const int* __restrict__ dst,
                                                   int* __restrict__ cnt, int ne) {
    int e = blockIdx.x * 256 + threadIdx.x;
    if (e < ne) atomicAdd(&cnt[dst[e]], 1);
}

__global__ __launch_bounds__(256) void dinv_kernel(const int* __restrict__ cnt,
                                                   float* __restrict__ dinv, int n) {
    int i = blockIdx.x * 256 + threadIdx.x;
    if (i < n) dinv[i] = 1.0f / sqrtf((float)(cnt[i] + 1));  // deg includes self loop
}

// single-block exclusive scan over cnt -> row_ptr (and cursor copy)
__global__ __launch_bounds__(1024) void scan_kernel(const int* __restrict__ cnt,
                                                    int* __restrict__ row_ptr,
                                                    int* __restrict__ cursor, int n) {
    constexpr int VPT = 8;
    __shared__ int wsums[16];
    int t = threadIdx.x;
    int wave = t >> 6, lane = t & 63;
    int carry = 0;
    for (int base = 0; base < n; base += 1024 * VPT) {
        int i0 = base + t * VPT;
        int v[VPT];
        int run = 0;
        #pragma unroll
        for (int j = 0; j < VPT; ++j) {
            int idx = i0 + j;
            int a = (idx < n) ? cnt[idx] : 0;
            v[j] = run;
            run += a;
        }
        int x = run;  // wave-level inclusive scan of per-thread totals
        #pragma unroll
        for (int off = 1; off < 64; off <<= 1) {
            int y = __shfl_up(x, off, 64);
            if (lane >= off) x += y;
        }
        if (lane == 63) wsums[wave] = x;
        __syncthreads();
        if (t < 16) {
            int w = wsums[t];
            #pragma unroll
            for (int off = 1; off < 16; off <<= 1) {
                int y = __shfl_up(w, off, 64);
                if (t >= off) w += y;
            }
            wsums[t] = w;  // inclusive across waves
        }
        __syncthreads();
        int wave_off = (wave == 0) ? 0 : wsums[wave - 1];
        int base_off = carry + wave_off + (x - run);
        #pragma unroll
        for (int j = 0; j < VPT; ++j) {
            int idx = i0 + j;
            if (idx < n) {
                int val = base_off + v[j];
                row_ptr[idx] = val;
                cursor[idx] = val;
            }
        }
        carry += wsums[15];
        __syncthreads();
    }
    if (t == 0) row_ptr[n] = carry;
}

__global__ __launch_bounds__(256) void scatter_kernel(const int* __restrict__ src,
                                                      const int* __restrict__ dst,
                                                      int* __restrict__ cursor,
                                                      int* __restrict__ col_idx, int ne) {
    int e = blockIdx.x * 256 + threadIdx.x;
    if (e < ne) {
        int d = dst[e];
        int pos = atomicAdd(&cursor[d], 1);
        col_idx[pos] = src[e];
    }
}

// ---------------- dense GEMM: Y = X @ W, epilogue EPI: 0 -> *dinv[row], 1 -> tanh(+bias) ----------------
template<int K, int FOUT, int EPI>
__global__ __launch_bounds__(256) void gemm_kernel(const float* __restrict__ X,
        const float* __restrict__ W, const float* __restrict__ bias,
        const float* __restrict__ dinv, float* __restrict__ Y, int nrows) {
    __shared__ float Wl[K * FOUT];
    for (int i = threadIdx.x; i < K * FOUT; i += 256) Wl[i] = W[i];
    __syncthreads();
    int idx = blockIdx.x * 256 + threadIdx.x;
    int total = nrows * FOUT;
    if (idx >= total) return;
    int row = idx / FOUT;
    int col = idx - row * FOUT;
    const float* xr = X + (size_t)row * K;
    float acc = 0.f;
    #pragma unroll 8
    for (int k = 0; k < K; ++k) acc = fmaf(xr[k], Wl[k * FOUT + col], acc);
    if (EPI == 0) acc *= dinv[row];
    else          acc = tanhf(acc + bias[col]);
    Y[idx] = acc;
}

// ---------------- CSR aggregation: acc = Z[i] + sum_{s in row(i)} Z[s]; out = dinv*acc (+bias,tanh) ----------------
template<int F, bool FINAL>
__global__ __launch_bounds__(256) void aggregate_kernel(const float* __restrict__ Z,
        const int* __restrict__ row_ptr, const int* __restrict__ col_idx,
        const float* __restrict__ dinv, const float* __restrict__ bias,
        float* __restrict__ out, int n) {
    constexpr int NPW = 64 / F;  // nodes per wave (1 for F=64, 2 for F=32)
    int tid = threadIdx.x;
    int wave = tid >> 6, lane = tid & 63;
    int sub = lane / F;
    int f = lane - sub * F;
    int node = blockIdx.x * (4 * NPW) + wave * NPW + sub;
    bool valid = node < n;
    int nd = valid ? node : 0;
    int start = valid ? row_ptr[nd] : 0;
    int end   = valid ? row_ptr[nd + 1] : 0;
    float acc = valid ? Z[(size_t)nd * F + f] : 0.f;  // self-loop term
    for (int base = start; base < end; base += F) {
        int j = base + f;
        int idxv = (j < end) ? col_idx[j] : 0;
        int m = min(F, end - base);
        for (int t2 = 0; t2 < m; ++t2) {
            int s = __shfl(idxv, sub * F + t2, 64);  // broadcast within the F-lane group
            acc += Z[(size_t)s * F + f];
        }
    }
    if (valid) {
        float r = dinv[nd] * acc;
        if (FINAL) r = tanhf(r + bias[f]);
        out[(size_t)nd * F + f] = r;
    }
}

__global__ __launch_bounds__(256) void mul_dinv_kernel(const float* __restrict__ h,
        const float* __restrict__ dinv, float* __restrict__ Z, int total, int shift) {
    int idx = blockIdx.x * 256 + threadIdx.x;
    if (idx < total) Z[idx] = h[idx] * dinv[idx >> shift];
}

// ---------------- final: e = [h[src], h[dst]], out = e @ Wc + bc ----------------
__global__ __launch_bounds__(256) void edge_kernel(const int* __restrict__ src,
        const int* __restrict__ dst, const float* __restrict__ h,
        const float* __restrict__ Wc, const float* __restrict__ bc,
        float* __restrict__ out, float* __restrict__ efeat, int ne) {
    __shared__ float Wl[144];
    __shared__ float bl[6];
    if (threadIdx.x < 144) Wl[threadIdx.x] = Wc[threadIdx.x];
    if (threadIdx.x < 6) bl[threadIdx.x] = bc[threadIdx.x];
    __syncthreads();
    int e = blockIdx.x * 256 + threadIdx.x;
    if (e >= ne) return;
    int s = src[e], d = dst[e];
    const float4* hs4 = (const float4*)(h + (size_t)s * 12);
    const float4* hd4 = (const float4*)(h + (size_t)d * 12);
    float4 v0 = hs4[0], v1 = hs4[1], v2 = hs4[2];
    float4 v3 = hd4[0], v4 = hd4[1], v5 = hd4[2];
    float v[24];
    ((float4*)v)[0] = v0; ((float4*)v)[1] = v1; ((float4*)v)[2] = v2;
    ((float4*)v)[3] = v3; ((float4*)v)[4] = v4; ((float4*)v)[5] = v5;
    float4* ef4 = (float4*)(efeat + (size_t)e * 24);
    ef4[0] = v0; ef4[1] = v1; ef4[2] = v2; ef4[3] = v3; ef4[4] = v4; ef4[5] = v5;
    float o[6];
    #pragma unroll
    for (int c = 0; c < 6; ++c) {
        float acc = bl[c];
        #pragma unroll
        for (int k = 0; k < 24; ++k) acc = fmaf(v[k], Wl[k * 6 + c], acc);
        o[c] = acc;
    }
    float2* o2 = (float2*)(out + (size_t)e * 6);
    o2[0] = make_float2(o[0], o[1]);
    o2[1] = make_float2(o[2], o[3]);
    o2[2] = make_float2(o[4], o[5]);
}

extern "C" void kernel_launch(void* const* d_in, const int* in_sizes, int n_in,
                              void* d_out, int out_size, void* d_ws, size_t ws_size,
                              hipStream_t stream) {
    const int N = in_sizes[0] / 128;
    const int E = in_sizes[1] / 2;

    const float* x   = (const float*)d_in[0];
    const int*   ei  = (const int*)d_in[1];
    const int*   srcE = ei;
    const int*   dstE = ei + E;
    const float* W1 = (const float*)d_in[3];  const float* b1 = (const float*)d_in[4];
    const float* W2 = (const float*)d_in[5];  const float* b2 = (const float*)d_in[6];
    const float* W3 = (const float*)d_in[7];  const float* b3 = (const float*)d_in[8];
    const float* W4 = (const float*)d_in[9];  const float* b4 = (const float*)d_in[10];
    const float* W5 = (const float*)d_in[11]; const float* b5 = (const float*)d_in[12];
    const float* Wl1 = (const float*)d_in[13]; const float* bl1 = (const float*)d_in[14];
    const float* Wl2 = (const float*)d_in[15]; const float* bl2 = (const float*)d_in[16];
    const float* Wl3 = (const float*)d_in[17]; const float* bl3 = (const float*)d_in[18];
    const float* Wc  = (const float*)d_in[19]; const float* bc  = (const float*)d_in[20];

    // ---- workspace (small stuff only; big buffers live in d_out's e-region) ----
    char* ws = (char*)d_ws;
    size_t off = 0;
    auto take = [&](size_t bytes) -> char* {
        char* p = ws + off;
        off += (bytes + 255) & ~(size_t)255;
        return p;
    };
    int*   cnt     = (int*)take((size_t)N * 4);
    int*   row_ptr = (int*)take((size_t)(N + 1) * 4);
    int*   cursor  = (int*)take((size_t)N * 4);
    float* dinv    = (float*)take((size_t)N * 4);
    int*   col_idx = (int*)take((size_t)E * 4);
    float* h8      = (float*)take((size_t)N * 12 * 4);

    // big intermediate buffers inside d_out's e-region (dead until edge_kernel overwrites it)
    float* outbuf  = (float*)d_out;
    float* eregion = outbuf + (size_t)E * 6;
    float* bufZ = eregion;                       // up to N*64
    float* bufH = eregion + (size_t)N * 64;      // up to N*64
    float* bufC = eregion + (size_t)N * 128;     // N*256 (h5)

    int gE = (E + 255) / 256;
    int gN = (N + 255) / 256;
    auto gemm_blocks = [&](int fout) { return (N * fout + 255) / 256; };

    // ---- CSR build + norm ----
    hipMemsetAsync(cnt, 0, (size_t)N * 4, stream);
    hist_kernel<<<gE, 256, 0, stream>>>(dstE, cnt, E);
    dinv_kernel<<<gN, 256, 0, stream>>>(cnt, dinv, N);
    scan_kernel<<<1, 1024, 0, stream>>>(cnt, row_ptr, cursor, N);
    scatter_kernel<<<gE, 256, 0, stream>>>(srcE, dstE, cursor, col_idx, E);

    // ---- layer 1: 128 -> 64 ----
    gemm_kernel<128, 64, 0><<<gemm_blocks(64), 256, 0, stream>>>(x, W1, nullptr, dinv, bufZ, N);
    aggregate_kernel<64, true><<<(N + 3) / 4, 256, 0, stream>>>(bufZ, row_ptr, col_idx, dinv, b1, bufH, N);
    // ---- layer 2: 64 -> 64 ----
    gemm_kernel<64, 64, 0><<<gemm_blocks(64), 256, 0, stream>>>(bufH, W2, nullptr, dinv, bufZ, N);
    aggregate_kernel<64, true><<<(N + 3) / 4, 256, 0, stream>>>(bufZ, row_ptr, col_idx, dinv, b2, bufH, N);
    // ---- layer 3: 64 -> 32 ----
    gemm_kernel<64, 32, 0><<<gemm_blocks(32), 256, 0, stream>>>(bufH, W3, nullptr, dinv, bufZ, N);
    aggregate_kernel<32, true><<<(N + 7) / 8, 256, 0, stream>>>(bufZ, row_ptr, col_idx, dinv, b3, bufH, N);
    // ---- layer 4: 32 -> 32 ----
    gemm_kernel<32, 32, 0><<<gemm_blocks(32), 256, 0, stream>>>(bufH, W4, nullptr, dinv, bufZ, N);
    aggregate_kernel<32, true><<<(N + 7) / 8, 256, 0, stream>>>(bufZ, row_ptr, col_idx, dinv, b4, bufH, N);
    // ---- layer 5: aggregate first (32 wide), then 32 -> 256 GEMM ----
    mul_dinv_kernel<<<(N * 32 + 255) / 256, 256, 0, stream>>>(bufH, dinv, bufZ, N * 32, 5);
    aggregate_kernel<32, false><<<(N + 7) / 8, 256, 0, stream>>>(bufZ, row_ptr, col_idx, dinv, nullptr, bufH, N);
    gemm_kernel<32, 256, 1><<<gemm_blocks(256), 256, 0, stream>>>(bufH, W5, b5, nullptr, bufC, N);
    // ---- linear layers ----
    gemm_kernel<256, 24, 1><<<gemm_blocks(24), 256, 0, stream>>>(bufC, Wl1, bl1, nullptr, bufZ, N);
    gemm_kernel<24, 18, 1><<<gemm_blocks(18), 256, 0, stream>>>(bufZ, Wl2, bl2, nullptr, bufH, N);
    gemm_kernel<18, 12, 1><<<gemm_blocks(12), 256, 0, stream>>>(bufH, Wl3, bl3, nullptr, h8, N);
    // ---- edge output ----
    edge_kernel<<<gE, 256, 0, stream>>>(srcE, dstE, h8, Wc, bc, outbuf, eregion, E);
}

// Round 2
// 1762.310 us; speedup vs baseline: 1.1663x; 1.1663x over previous
//
#include <hip/hip_runtime.h>

// ---------------- CSR build ----------------
__global__ __launch_bounds__(256) void hist_kernel(const int* __restrict__ dst,
                                                   int* __restrict__ cnt, int ne) {
    int e = blockIdx.x * 256 + threadIdx.x;
    if (e < ne) atomicAdd(&cnt[dst[e]], 1);
}

__global__ __launch_bounds__(256) void dinv_kernel(const int* __restrict__ cnt,
                                                   float* __restrict__ dinv, int n) {
    int i = blockIdx.x * 256 + threadIdx.x;
    if (i < n) dinv[i] = 1.0f / sqrtf((float)(cnt[i] + 1));  // deg includes self loop
}

// single-block exclusive scan over cnt -> row_ptr (and cursor copy)
__global__ __launch_bounds__(1024) void scan_kernel(const int* __restrict__ cnt,
                                                    int* __restrict__ row_ptr,
                                                    int* __restrict__ cursor, int n) {
    constexpr int VPT = 8;
    __shared__ int wsums[16];
    int t = threadIdx.x;
    int wave = t >> 6, lane = t & 63;
    int carry = 0;
    for (int base = 0; base < n; base += 1024 * VPT) {
        int i0 = base + t * VPT;
        int v[VPT];
        int run = 0;
        #pragma unroll
        for (int j = 0; j < VPT; ++j) {
            int idx = i0 + j;
            int a = (idx < n) ? cnt[idx] : 0;
            v[j] = run;
            run += a;
        }
        int x = run;  // wave-level inclusive scan of per-thread totals
        #pragma unroll
        for (int off = 1; off < 64; off <<= 1) {
            int y = __shfl_up(x, off, 64);
            if (lane >= off) x += y;
        }
        if (lane == 63) wsums[wave] = x;
        __syncthreads();
        if (t < 16) {
            int w = wsums[t];
            #pragma unroll
            for (int off = 1; off < 16; off <<= 1) {
                int y = __shfl_up(w, off, 64);
                if (t >= off) w += y;
            }
            wsums[t] = w;  // inclusive across waves
        }
        __syncthreads();
        int wave_off = (wave == 0) ? 0 : wsums[wave - 1];
        int base_off = carry + wave_off + (x - run);
        #pragma unroll
        for (int j = 0; j < VPT; ++j) {
            int idx = i0 + j;
            if (idx < n) {
                int val = base_off + v[j];
                row_ptr[idx] = val;
                cursor[idx] = val;
            }
        }
        carry += wsums[15];
        __syncthreads();
    }
    if (t == 0) row_ptr[n] = carry;
}

__global__ __launch_bounds__(256) void scatter_kernel(const int* __restrict__ src,
                                                      const int* __restrict__ dst,
                                                      int* __restrict__ cursor,
                                                      int* __restrict__ col_idx, int ne) {
    int e = blockIdx.x * 256 + threadIdx.x;
    if (e < ne) {
        int d = dst[e];
        int pos = atomicAdd(&cursor[d], 1);
        col_idx[pos] = src[e];
    }
}

// ---------------- dense GEMM: Y = X @ W, epilogue EPI: 0 -> *dinv[row], 1 -> tanh(+bias) ----------------
template<int K, int FOUT, int EPI>
__global__ __launch_bounds__(256) void gemm_kernel(const float* __restrict__ X,
        const float* __restrict__ W, const float* __restrict__ bias,
        const float* __restrict__ dinv, float* __restrict__ Y, int nrows) {
    __shared__ float Wl[K * FOUT];
    for (int i = threadIdx.x; i < K * FOUT; i += 256) Wl[i] = W[i];
    __syncthreads();
    int idx = blockIdx.x * 256 + threadIdx.x;
    int total = nrows * FOUT;
    if (idx >= total) return;
    int row = idx / FOUT;
    int col = idx - row * FOUT;
    const float* xr = X + (size_t)row * K;
    float acc = 0.f;
    #pragma unroll 8
    for (int k = 0; k < K; ++k) acc = fmaf(xr[k], Wl[k * FOUT + col], acc);
    if (EPI == 0) acc *= dinv[row];
    else          acc = tanhf(acc + bias[col]);
    Y[idx] = acc;
}

// ---------------- CSR aggregation (vectorized) ----------------
// One wave per node. Lane layout: c = lane % (F/4) indexes a float4 feature quad,
// g = lane / (F/4) indexes a neighbor subgroup -> wave processes G neighbors per
// global_load_dwordx4 (G=4 for F=64, G=8 for F=32), giving G independent
// accumulation chains merged at the end by a shfl_xor tree.
template<int F, bool FINAL>
__global__ __launch_bounds__(256) void aggregate_kernel(const float* __restrict__ Z,
        const int* __restrict__ row_ptr, const int* __restrict__ col_idx,
        const float* __restrict__ dinv, const float* __restrict__ bias,
        float* __restrict__ out, int n) {
    constexpr int LPR = F / 4;      // lanes per neighbor row (16 or 8)
    constexpr int G   = 64 / LPR;   // neighbors per step (4 or 8)
    int tid = threadIdx.x;
    int wave = tid >> 6, lane = tid & 63;
    int g = lane / LPR;
    int c = lane - g * LPR;
    int node = blockIdx.x * 4 + wave;
    if (node >= n) return;
    int start = row_ptr[node];
    int end   = row_ptr[node + 1];
    float4 acc = make_float4(0.f, 0.f, 0.f, 0.f);
    // register window of up to 64 neighbor indices
    int wbase = start;
    int iv = (wbase + lane < end) ? col_idx[wbase + lane] : 0;
    #pragma unroll 2
    for (int base = start; base < end; base += G) {
        if (base - wbase == 64) {   // exhausted window -> refill
            wbase += 64;
            iv = (wbase + lane < end) ? col_idx[wbase + lane] : 0;
        }
        int s = __shfl(iv, (base - wbase) + g, 64);
        if (base + g < end) {
            const float4 v = *(const float4*)(Z + (size_t)s * F + c * 4);
            acc.x += v.x; acc.y += v.y; acc.z += v.z; acc.w += v.w;
        }
    }
    // merge the G neighbor-subgroup partials
    #pragma unroll
    for (int off = LPR; off < 64; off <<= 1) {
        acc.x += __shfl_xor(acc.x, off, 64);
        acc.y += __shfl_xor(acc.y, off, 64);
        acc.z += __shfl_xor(acc.z, off, 64);
        acc.w += __shfl_xor(acc.w, off, 64);
    }
    if (g == 0) {
        const float4 sv = *(const float4*)(Z + (size_t)node * F + c * 4);  // self loop
        float di = dinv[node];
        float4 r;
        r.x = di * (acc.x + sv.x);
        r.y = di * (acc.y + sv.y);
        r.z = di * (acc.z + sv.z);
        r.w = di * (acc.w + sv.w);
        if (FINAL) {
            const float4 bv = *(const float4*)(bias + c * 4);
            r.x = tanhf(r.x + bv.x);
            r.y = tanhf(r.y + bv.y);
            r.z = tanhf(r.z + bv.z);
            r.w = tanhf(r.w + bv.w);
        }
        *(float4*)(out + (size_t)node * F + c * 4) = r;
    }
}

__global__ __launch_bounds__(256) void mul_dinv_kernel(const float* __restrict__ h,
        const float* __restrict__ dinv, float* __restrict__ Z, int total, int shift) {
    int idx = blockIdx.x * 256 + threadIdx.x;
    if (idx < total) Z[idx] = h[idx] * dinv[idx >> shift];
}

// ---------------- final: e = [h[src], h[dst]], out = e @ Wc + bc ----------------
__global__ __launch_bounds__(256) void edge_kernel(const int* __restrict__ src,
        const int* __restrict__ dst, const float* __restrict__ h,
        const float* __restrict__ Wc, const float* __restrict__ bc,
        float* __restrict__ out, float* __restrict__ efeat, int ne) {
    __shared__ float Wl[144];
    __shared__ float bl[6];
    if (threadIdx.x < 144) Wl[threadIdx.x] = Wc[threadIdx.x];
    if (threadIdx.x < 6) bl[threadIdx.x] = bc[threadIdx.x];
    __syncthreads();
    int e = blockIdx.x * 256 + threadIdx.x;
    if (e >= ne) return;
    int s = src[e], d = dst[e];
    const float4* hs4 = (const float4*)(h + (size_t)s * 12);
    const float4* hd4 = (const float4*)(h + (size_t)d * 12);
    float4 v0 = hs4[0], v1 = hs4[1], v2 = hs4[2];
    float4 v3 = hd4[0], v4 = hd4[1], v5 = hd4[2];
    float v[24];
    ((float4*)v)[0] = v0; ((float4*)v)[1] = v1; ((float4*)v)[2] = v2;
    ((float4*)v)[3] = v3; ((float4*)v)[4] = v4; ((float4*)v)[5] = v5;
    float4* ef4 = (float4*)(efeat + (size_t)e * 24);
    ef4[0] = v0; ef4[1] = v1; ef4[2] = v2; ef4[3] = v3; ef4[4] = v4; ef4[5] = v5;
    float o[6];
    #pragma unroll
    for (int c = 0; c < 6; ++c) {
        float acc = bl[c];
        #pragma unroll
        for (int k = 0; k < 24; ++k) acc = fmaf(v[k], Wl[k * 6 + c], acc);
        o[c] = acc;
    }
    float2* o2 = (float2*)(out + (size_t)e * 6);
    o2[0] = make_float2(o[0], o[1]);
    o2[1] = make_float2(o[2], o[3]);
    o2[2] = make_float2(o[4], o[5]);
}

extern "C" void kernel_launch(void* const* d_in, const int* in_sizes, int n_in,
                              void* d_out, int out_size, void* d_ws, size_t ws_size,
                              hipStream_t stream) {
    const int N = in_sizes[0] / 128;
    const int E = in_sizes[1] / 2;

    const float* x   = (const float*)d_in[0];
    const int*   ei  = (const int*)d_in[1];
    const int*   srcE = ei;
    const int*   dstE = ei + E;
    const float* W1 = (const float*)d_in[3];  const float* b1 = (const float*)d_in[4];
    const float* W2 = (const float*)d_in[5];  const float* b2 = (const float*)d_in[6];
    const float* W3 = (const float*)d_in[7];  const float* b3 = (const float*)d_in[8];
    const float* W4 = (const float*)d_in[9];  const float* b4 = (const float*)d_in[10];
    const float* W5 = (const float*)d_in[11]; const float* b5 = (const float*)d_in[12];
    const float* Wl1 = (const float*)d_in[13]; const float* bl1 = (const float*)d_in[14];
    const float* Wl2 = (const float*)d_in[15]; const float* bl2 = (const float*)d_in[16];
    const float* Wl3 = (const float*)d_in[17]; const float* bl3 = (const float*)d_in[18];
    const float* Wc  = (const float*)d_in[19]; const float* bc  = (const float*)d_in[20];

    // ---- workspace (small stuff only; big buffers live in d_out's e-region) ----
    char* ws = (char*)d_ws;
    size_t off = 0;
    auto take = [&](size_t bytes) -> char* {
        char* p = ws + off;
        off += (bytes + 255) & ~(size_t)255;
        return p;
    };
    int*   cnt     = (int*)take((size_t)N * 4);
    int*   row_ptr = (int*)take((size_t)(N + 1) * 4);
    int*   cursor  = (int*)take((size_t)N * 4);
    float* dinv    = (float*)take((size_t)N * 4);
    int*   col_idx = (int*)take((size_t)E * 4);
    float* h8      = (float*)take((size_t)N * 12 * 4);

    // big intermediate buffers inside d_out's e-region (dead until edge_kernel overwrites it)
    float* outbuf  = (float*)d_out;
    float* eregion = outbuf + (size_t)E * 6;
    float* bufZ = eregion;                       // up to N*64
    float* bufH = eregion + (size_t)N * 64;      // up to N*64
    float* bufC = eregion + (size_t)N * 128;     // N*256 (h5)

    int gE = (E + 255) / 256;
    int gN = (N + 255) / 256;
    int gAgg = (N + 3) / 4;                      // 1 node per wave, 4 waves per block
    auto gemm_blocks = [&](int fout) { return (N * fout + 255) / 256; };

    // ---- CSR build + norm ----
    hipMemsetAsync(cnt, 0, (size_t)N * 4, stream);
    hist_kernel<<<gE, 256, 0, stream>>>(dstE, cnt, E);
    dinv_kernel<<<gN, 256, 0, stream>>>(cnt, dinv, N);
    scan_kernel<<<1, 1024, 0, stream>>>(cnt, row_ptr, cursor, N);
    scatter_kernel<<<gE, 256, 0, stream>>>(srcE, dstE, cursor, col_idx, E);

    // ---- layer 1: 128 -> 64 ----
    gemm_kernel<128, 64, 0><<<gemm_blocks(64), 256, 0, stream>>>(x, W1, nullptr, dinv, bufZ, N);
    aggregate_kernel<64, true><<<gAgg, 256, 0, stream>>>(bufZ, row_ptr, col_idx, dinv, b1, bufH, N);
    // ---- layer 2: 64 -> 64 ----
    gemm_kernel<64, 64, 0><<<gemm_blocks(64), 256, 0, stream>>>(bufH, W2, nullptr, dinv, bufZ, N);
    aggregate_kernel<64, true><<<gAgg, 256, 0, stream>>>(bufZ, row_ptr, col_idx, dinv, b2, bufH, N);
    // ---- layer 3: 64 -> 32 ----
    gemm_kernel<64, 32, 0><<<gemm_blocks(32), 256, 0, stream>>>(bufH, W3, nullptr, dinv, bufZ, N);
    aggregate_kernel<32, true><<<gAgg, 256, 0, stream>>>(bufZ, row_ptr, col_idx, dinv, b3, bufH, N);
    // ---- layer 4: 32 -> 32 ----
    gemm_kernel<32, 32, 0><<<gemm_blocks(32), 256, 0, stream>>>(bufH, W4, nullptr, dinv, bufZ, N);
    aggregate_kernel<32, true><<<gAgg, 256, 0, stream>>>(bufZ, row_ptr, col_idx, dinv, b4, bufH, N);
    // ---- layer 5: aggregate first (32 wide), then 32 -> 256 GEMM ----
    mul_dinv_kernel<<<(N * 32 + 255) / 256, 256, 0, stream>>>(bufH, dinv, bufZ, N * 32, 5);
    aggregate_kernel<32, false><<<gAgg, 256, 0, stream>>>(bufZ, row_ptr, col_idx, dinv, nullptr, bufH, N);
    gemm_kernel<32, 256, 1><<<gemm_blocks(256), 256, 0, stream>>>(bufH, W5, b5, nullptr, bufC, N);
    // ---- linear layers ----
    gemm_kernel<256, 24, 1><<<gemm_blocks(24), 256, 0, stream>>>(bufC, Wl1, bl1, nullptr, bufZ, N);
    gemm_kernel<24, 18, 1><<<gemm_blocks(18), 256, 0, stream>>>(bufZ, Wl2, bl2, nullptr, bufH, N);
    gemm_kernel<18, 12, 1><<<gemm_blocks(12), 256, 0, stream>>>(bufH, Wl3, bl3, nullptr, h8, N);
    // ---- edge output ----
    edge_kernel<<<gE, 256, 0, stream>>>(srcE, dstE, h8, Wc, bc, outbuf, eregion, E);
}

// Round 3
// 1469.853 us; speedup vs baseline: 1.3983x; 1.1990x over previous
//
#include <hip/hip_runtime.h>

constexpr int BKT_SHIFT = 7;     // 128 nodes per bucket
constexpr int NBKT_PAD  = 1024;  // padded bucket count (real: ceil(N/128) = 782)
constexpr int CHUNK     = 8192;  // edges per partition block
constexpr int MAXSEG    = 6144;  // LDS staging capacity per bucket (mean ~4096)

// ---- K1: per-chunk bucket histogram (LDS atomics only) ----
__global__ __launch_bounds__(256) void k1_hist(const int* __restrict__ dst,
                                               int* __restrict__ Hist, int ne) {
    __shared__ int lh[NBKT_PAD];
    for (int i = threadIdx.x; i < NBKT_PAD; i += 256) lh[i] = 0;
    __syncthreads();
    int base = blockIdx.x * CHUNK;
    int lim = min(CHUNK, ne - base);
    for (int i = threadIdx.x; i < lim; i += 256)
        atomicAdd(&lh[dst[base + i] >> BKT_SHIFT], 1);
    __syncthreads();
    for (int i = threadIdx.x; i < NBKT_PAD; i += 256)
        Hist[(size_t)blockIdx.x * NBKT_PAD + i] = lh[i];
}

// ---- K2: single block. bucket bases + rewrite Hist to absolute scatter offsets ----
__global__ __launch_bounds__(1024) void k2_scan(int* __restrict__ Hist,
                                                int* __restrict__ bktBase,
                                                int* __restrict__ row_ptrN, int nblk) {
    __shared__ int wsums[16];
    int t = threadIdx.x, wave = t >> 6, lane = t & 63;
    int tot = 0;
    for (int blk = 0; blk < nblk; ++blk) tot += Hist[(size_t)blk * NBKT_PAD + t];
    int x = tot;
    #pragma unroll
    for (int off = 1; off < 64; off <<= 1) {
        int y = __shfl_up(x, off, 64);
        if (lane >= off) x += y;
    }
    if (lane == 63) wsums[wave] = x;
    __syncthreads();
    if (t < 16) {
        int w = wsums[t];
        #pragma unroll
        for (int off = 1; off < 16; off <<= 1) {
            int y = __shfl_up(w, off, 64);
            if (t >= off) w += y;
        }
        wsums[t] = w;
    }
    __syncthreads();
    int excl = (wave ? wsums[wave - 1] : 0) + (x - tot);
    bktBase[t] = excl;
    if (t == 1023) { bktBase[1024] = excl + tot; *row_ptrN = excl + tot; }
    int run = excl;
    for (int blk = 0; blk < nblk; ++blk) {
        size_t idx = (size_t)blk * NBKT_PAD + t;
        int v = Hist[idx];
        Hist[idx] = run;
        run += v;
    }
}

// ---- K3: partition edges into bucket streams (LDS cursors, no global atomics) ----
__global__ __launch_bounds__(256) void k3_partition(const int* __restrict__ src,
                                                    const int* __restrict__ dst,
                                                    const int* __restrict__ Hist,
                                                    int* __restrict__ srcS,
                                                    int* __restrict__ dstS, int ne) {
    __shared__ int cur[NBKT_PAD];
    for (int i = threadIdx.x; i < NBKT_PAD; i += 256)
        cur[i] = Hist[(size_t)blockIdx.x * NBKT_PAD + i];
    __syncthreads();
    int base = blockIdx.x * CHUNK;
    int lim = min(CHUNK, ne - base);
    for (int i = threadIdx.x; i < lim; i += 256) {
        int d = dst[base + i];
        int s = src[base + i];
        int pos = atomicAdd(&cur[d >> BKT_SHIFT], 1);
        srcS[pos] = s;
        dstS[pos] = d;
    }
}

// ---- K4: per-bucket fine CSR (counting sort over 128 nodes) + row_ptr + dinv ----
__global__ __launch_bounds__(256) void k4_csr(const int* __restrict__ srcS,
                                              const int* __restrict__ dstS,
                                              const int* __restrict__ bktBase,
                                              int* __restrict__ col_idx,
                                              int* __restrict__ row_ptr,
                                              float* __restrict__ dinv, int n) {
    __shared__ int hist[128];
    __shared__ int rbase[128];
    __shared__ int cur[128];
    __shared__ int stage[MAXSEG];
    int b = blockIdx.x;
    int segs = bktBase[b], sege = bktBase[b + 1];
    int seglen = sege - segs;
    int node0 = b << BKT_SHIFT;
    int nloc = min(128, n - node0);
    int t = threadIdx.x;
    if (t < 128) hist[t] = 0;
    __syncthreads();
    for (int i = t; i < seglen; i += 256)
        atomicAdd(&hist[dstS[segs + i] - node0], 1);
    __syncthreads();
    if (t < 64) {  // wave 0: exclusive scan of 128 counters, 2 per lane
        int a0 = hist[2 * t], a1 = hist[2 * t + 1];
        int pair = a0 + a1;
        int x = pair;
        #pragma unroll
        for (int off = 1; off < 64; off <<= 1) {
            int y = __shfl_up(x, off, 64);
            if (t >= off) x += y;
        }
        int excl = x - pair;
        rbase[2 * t] = excl;       rbase[2 * t + 1] = excl + a0;
        cur[2 * t]   = excl;       cur[2 * t + 1]   = excl + a0;
    }
    __syncthreads();
    if (seglen <= MAXSEG) {
        for (int i = t; i < seglen; i += 256) {
            int d = dstS[segs + i] - node0;
            int pos = atomicAdd(&cur[d], 1);
            stage[pos] = srcS[segs + i];
        }
        __syncthreads();
        for (int i = t; i < seglen; i += 256)
            col_idx[segs + i] = stage[i];
    } else {  // overflow fallback: direct (rare with uniform graphs)
        for (int i = t; i < seglen; i += 256) {
            int d = dstS[segs + i] - node0;
            int pos = atomicAdd(&cur[d], 1);
            col_idx[segs + pos] = srcS[segs + i];
        }
    }
    if (t < nloc) {
        row_ptr[node0 + t] = segs + rbase[t];
        dinv[node0 + t] = 1.0f / sqrtf((float)(hist[t] + 1));  // deg incl self loop
    }
}

// ---------------- dense GEMM: Y = X @ W, epilogue EPI: 0 -> *dinv[row], 1 -> tanh(+bias) ----------------
template<int K, int FOUT, int EPI>
__global__ __launch_bounds__(256) void gemm_kernel(const float* __restrict__ X,
        const float* __restrict__ W, const float* __restrict__ bias,
        const float* __restrict__ dinv, float* __restrict__ Y, int nrows) {
    __shared__ float Wl[K * FOUT];
    for (int i = threadIdx.x; i < K * FOUT; i += 256) Wl[i] = W[i];
    __syncthreads();
    int idx = blockIdx.x * 256 + threadIdx.x;
    int total = nrows * FOUT;
    if (idx >= total) return;
    int row = idx / FOUT;
    int col = idx - row * FOUT;
    const float* xr = X + (size_t)row * K;
    float acc = 0.f;
    #pragma unroll 8
    for (int k = 0; k < K; ++k) acc = fmaf(xr[k], Wl[k * FOUT + col], acc);
    if (EPI == 0) acc *= dinv[row];
    else          acc = tanhf(acc + bias[col]);
    Y[idx] = acc;
}

// ---------------- CSR aggregation (vectorized) ----------------
template<int F, bool FINAL>
__global__ __launch_bounds__(256) void aggregate_kernel(const float* __restrict__ Z,
        const int* __restrict__ row_ptr, const int* __restrict__ col_idx,
        const float* __restrict__ dinv, const float* __restrict__ bias,
        float* __restrict__ out, int n) {
    constexpr int LPR = F / 4;      // lanes per neighbor row (16 or 8)
    constexpr int G   = 64 / LPR;   // neighbors per step (4 or 8)
    int tid = threadIdx.x;
    int wave = tid >> 6, lane = tid & 63;
    int g = lane / LPR;
    int c = lane - g * LPR;
    int node = blockIdx.x * 4 + wave;
    if (node >= n) return;
    int start = row_ptr[node];
    int end   = row_ptr[node + 1];
    float4 acc = make_float4(0.f, 0.f, 0.f, 0.f);
    int wbase = start;
    int iv = (wbase + lane < end) ? col_idx[wbase + lane] : 0;
    #pragma unroll 2
    for (int base = start; base < end; base += G) {
        if (base - wbase == 64) {
            wbase += 64;
            iv = (wbase + lane < end) ? col_idx[wbase + lane] : 0;
        }
        int s = __shfl(iv, (base - wbase) + g, 64);
        if (base + g < end) {
            const float4 v = *(const float4*)(Z + (size_t)s * F + c * 4);
            acc.x += v.x; acc.y += v.y; acc.z += v.z; acc.w += v.w;
        }
    }
    #pragma unroll
    for (int off = LPR; off < 64; off <<= 1) {
        acc.x += __shfl_xor(acc.x, off, 64);
        acc.y += __shfl_xor(acc.y, off, 64);
        acc.z += __shfl_xor(acc.z, off, 64);
        acc.w += __shfl_xor(acc.w, off, 64);
    }
    if (g == 0) {
        const float4 sv = *(const float4*)(Z + (size_t)node * F + c * 4);
        float di = dinv[node];
        float4 r;
        r.x = di * (acc.x + sv.x);
        r.y = di * (acc.y + sv.y);
        r.z = di * (acc.z + sv.z);
        r.w = di * (acc.w + sv.w);
        if (FINAL) {
            const float4 bv = *(const float4*)(bias + c * 4);
            r.x = tanhf(r.x + bv.x);
            r.y = tanhf(r.y + bv.y);
            r.z = tanhf(r.z + bv.z);
            r.w = tanhf(r.w + bv.w);
        }
        *(float4*)(out + (size_t)node * F + c * 4) = r;
    }
}

__global__ __launch_bounds__(256) void mul_dinv_kernel(const float* __restrict__ h,
        const float* __restrict__ dinv, float* __restrict__ Z, int total, int shift) {
    int idx = blockIdx.x * 256 + threadIdx.x;
    if (idx < total) Z[idx] = h[idx] * dinv[idx >> shift];
}

// ---------------- final: e = [h[src], h[dst]], out = e @ Wc + bc ----------------
__global__ __launch_bounds__(256) void edge_kernel(const int* __restrict__ src,
        const int* __restrict__ dst, const float* __restrict__ h,
        const float* __restrict__ Wc, const float* __restrict__ bc,
        float* __restrict__ out, float* __restrict__ efeat, int ne) {
    __shared__ float Wl[144];
    __shared__ float bl[6];
    if (threadIdx.x < 144) Wl[threadIdx.x] = Wc[threadIdx.x];
    if (threadIdx.x < 6) bl[threadIdx.x] = bc[threadIdx.x];
    __syncthreads();
    int e = blockIdx.x * 256 + threadIdx.x;
    if (e >= ne) return;
    int s = src[e], d = dst[e];
    const float4* hs4 = (const float4*)(h + (size_t)s * 12);
    const float4* hd4 = (const float4*)(h + (size_t)d * 12);
    float4 v0 = hs4[0], v1 = hs4[1], v2 = hs4[2];
    float4 v3 = hd4[0], v4 = hd4[1], v5 = hd4[2];
    float v[24];
    ((float4*)v)[0] = v0; ((float4*)v)[1] = v1; ((float4*)v)[2] = v2;
    ((float4*)v)[3] = v3; ((float4*)v)[4] = v4; ((float4*)v)[5] = v5;
    float4* ef4 = (float4*)(efeat + (size_t)e * 24);
    ef4[0] = v0; ef4[1] = v1; ef4[2] = v2; ef4[3] = v3; ef4[4] = v4; ef4[5] = v5;
    float o[6];
    #pragma unroll
    for (int c = 0; c < 6; ++c) {
        float acc = bl[c];
        #pragma unroll
        for (int k = 0; k < 24; ++k) acc = fmaf(v[k], Wl[k * 6 + c], acc);
        o[c] = acc;
    }
    float2* o2 = (float2*)(out + (size_t)e * 6);
    o2[0] = make_float2(o[0], o[1]);
    o2[1] = make_float2(o[2], o[3]);
    o2[2] = make_float2(o[4], o[5]);
}

extern "C" void kernel_launch(void* const* d_in, const int* in_sizes, int n_in,
                              void* d_out, int out_size, void* d_ws, size_t ws_size,
                              hipStream_t stream) {
    const int N = in_sizes[0] / 128;
    const int E = in_sizes[1] / 2;

    const float* x   = (const float*)d_in[0];
    const int*   ei  = (const int*)d_in[1];
    const int*   srcE = ei;
    const int*   dstE = ei + E;
    const float* W1 = (const float*)d_in[3];  const float* b1 = (const float*)d_in[4];
    const float* W2 = (const float*)d_in[5];  const float* b2 = (const float*)d_in[6];
    const float* W3 = (const float*)d_in[7];  const float* b3 = (const float*)d_in[8];
    const float* W4 = (const float*)d_in[9];  const float* b4 = (const float*)d_in[10];
    const float* W5 = (const float*)d_in[11]; const float* b5 = (const float*)d_in[12];
    const float* Wl1 = (const float*)d_in[13]; const float* bl1 = (const float*)d_in[14];
    const float* Wl2 = (const float*)d_in[15]; const float* bl2 = (const float*)d_in[16];
    const float* Wl3 = (const float*)d_in[17]; const float* bl3 = (const float*)d_in[18];
    const float* Wc  = (const float*)d_in[19]; const float* bc  = (const float*)d_in[20];

    // ---- workspace (small persistent arrays) ----
    char* ws = (char*)d_ws;
    size_t off = 0;
    auto take = [&](size_t bytes) -> char* {
        char* p = ws + off;
        off += (bytes + 255) & ~(size_t)255;
        return p;
    };
    int*   row_ptr = (int*)take((size_t)(N + 1) * 4);
    float* dinv    = (float*)take((size_t)N * 4);
    int*   col_idx = (int*)take((size_t)E * 4);
    float* h8      = (float*)take((size_t)N * 12 * 4);
    int*   bktBase = (int*)take((size_t)(NBKT_PAD + 1) * 4);

    // big/transient buffers inside d_out's e-region (dead until edge_kernel overwrites it)
    float* outbuf  = (float*)d_out;
    float* eregion = outbuf + (size_t)E * 6;
    // CSR-build transients (consumed before layer 1):
    int* srcS = (int*)eregion;
    int* dstS = srcS + E;
    int* Hist = dstS + E;
    // layer buffers (live after CSR build):
    float* bufZ = eregion;                       // up to N*64
    float* bufH = eregion + (size_t)N * 64;      // up to N*64
    float* bufC = eregion + (size_t)N * 128;     // N*256 (h5)

    int gE = (E + 255) / 256;
    int gAgg = (N + 3) / 4;
    int nblk = (E + CHUNK - 1) / CHUNK;
    int nbkt = (N + 127) >> BKT_SHIFT;
    auto gemm_blocks = [&](int fout) { return (N * fout + 255) / 256; };

    // ---- CSR build (no global atomics) ----
    k1_hist<<<nblk, 256, 0, stream>>>(dstE, Hist, E);
    k2_scan<<<1, 1024, 0, stream>>>(Hist, bktBase, row_ptr + N, nblk);
    k3_partition<<<nblk, 256, 0, stream>>>(srcE, dstE, Hist, srcS, dstS, E);
    k4_csr<<<nbkt, 256, 0, stream>>>(srcS, dstS, bktBase, col_idx, row_ptr, dinv, N);

    // ---- layer 1: 128 -> 64 ----
    gemm_kernel<128, 64, 0><<<gemm_blocks(64), 256, 0, stream>>>(x, W1, nullptr, dinv, bufZ, N);
    aggregate_kernel<64, true><<<gAgg, 256, 0, stream>>>(bufZ, row_ptr, col_idx, dinv, b1, bufH, N);
    // ---- layer 2: 64 -> 64 ----
    gemm_kernel<64, 64, 0><<<gemm_blocks(64), 256, 0, stream>>>(bufH, W2, nullptr, dinv, bufZ, N);
    aggregate_kernel<64, true><<<gAgg, 256, 0, stream>>>(bufZ, row_ptr, col_idx, dinv, b2, bufH, N);
    // ---- layer 3: 64 -> 32 ----
    gemm_kernel<64, 32, 0><<<gemm_blocks(32), 256, 0, stream>>>(bufH, W3, nullptr, dinv, bufZ, N);
    aggregate_kernel<32, true><<<gAgg, 256, 0, stream>>>(bufZ, row_ptr, col_idx, dinv, b3, bufH, N);
    // ---- layer 4: 32 -> 32 ----
    gemm_kernel<32, 32, 0><<<gemm_blocks(32), 256, 0, stream>>>(bufH, W4, nullptr, dinv, bufZ, N);
    aggregate_kernel<32, true><<<gAgg, 256, 0, stream>>>(bufZ, row_ptr, col_idx, dinv, b4, bufH, N);
    // ---- layer 5: aggregate first (32 wide), then 32 -> 256 GEMM ----
    mul_dinv_kernel<<<(N * 32 + 255) / 256, 256, 0, stream>>>(bufH, dinv, bufZ, N * 32, 5);
    aggregate_kernel<32, false><<<gAgg, 256, 0, stream>>>(bufZ, row_ptr, col_idx, dinv, nullptr, bufH, N);
    gemm_kernel<32, 256, 1><<<gemm_blocks(256), 256, 0, stream>>>(bufH, W5, b5, nullptr, bufC, N);
    // ---- linear layers ----
    gemm_kernel<256, 24, 1><<<gemm_blocks(24), 256, 0, stream>>>(bufC, Wl1, bl1, nullptr, bufZ, N);
    gemm_kernel<24, 18, 1><<<gemm_blocks(18), 256, 0, stream>>>(bufZ, Wl2, bl2, nullptr, bufH, N);
    gemm_kernel<18, 12, 1><<<gemm_blocks(12), 256, 0, stream>>>(bufH, Wl3, bl3, nullptr, h8, N);
    // ---- edge output ----
    edge_kernel<<<gE, 256, 0, stream>>>(srcE, dstE, h8, Wc, bc, outbuf, eregion, E);
}

// Round 4
// 1081.418 us; speedup vs baseline: 1.9006x; 1.3592x over previous
//
#include <hip/hip_runtime.h>

constexpr int BKT_SHIFT = 7;     // 128 nodes per bucket
constexpr int NBKT_PAD  = 1024;  // padded bucket count (real: ceil(N/128) = 782)
constexpr int CHUNK     = 8192;  // edges per partition block
constexpr int MAXSEG    = 6144;  // LDS staging capacity per bucket (mean ~4096)

// ---- K1: per-chunk bucket histogram (LDS atomics only) ----
__global__ __launch_bounds__(256) void k1_hist(const int* __restrict__ dst,
                                               int* __restrict__ Hist, int ne) {
    __shared__ int lh[NBKT_PAD];
    for (int i = threadIdx.x; i < NBKT_PAD; i += 256) lh[i] = 0;
    __syncthreads();
    int base = blockIdx.x * CHUNK;
    int lim = min(CHUNK, ne - base);
    for (int i = threadIdx.x; i < lim; i += 256)
        atomicAdd(&lh[dst[base + i] >> BKT_SHIFT], 1);
    __syncthreads();
    for (int i = threadIdx.x; i < NBKT_PAD; i += 256)
        Hist[(size_t)blockIdx.x * NBKT_PAD + i] = lh[i];
}

// ---- K2: single block. bucket bases + rewrite Hist to absolute scatter offsets ----
__global__ __launch_bounds__(1024) void k2_scan(int* __restrict__ Hist,
                                                int* __restrict__ bktBase,
                                                int* __restrict__ row_ptrN, int nblk) {
    __shared__ int wsums[16];
    int t = threadIdx.x, wave = t >> 6, lane = t & 63;
    int tot = 0;
    for (int blk = 0; blk < nblk; ++blk) tot += Hist[(size_t)blk * NBKT_PAD + t];
    int x = tot;
    #pragma unroll
    for (int off = 1; off < 64; off <<= 1) {
        int y = __shfl_up(x, off, 64);
        if (lane >= off) x += y;
    }
    if (lane == 63) wsums[wave] = x;
    __syncthreads();
    if (t < 16) {
        int w = wsums[t];
        #pragma unroll
        for (int off = 1; off < 16; off <<= 1) {
            int y = __shfl_up(w, off, 64);
            if (t >= off) w += y;
        }
        wsums[t] = w;
    }
    __syncthreads();
    int excl = (wave ? wsums[wave - 1] : 0) + (x - tot);
    bktBase[t] = excl;
    if (t == 1023) { bktBase[1024] = excl + tot; *row_ptrN = excl + tot; }
    int run = excl;
    for (int blk = 0; blk < nblk; ++blk) {
        size_t idx = (size_t)blk * NBKT_PAD + t;
        int v = Hist[idx];
        Hist[idx] = run;
        run += v;
    }
}

// ---- K3: partition edges into bucket streams (LDS cursors, no global atomics) ----
__global__ __launch_bounds__(256) void k3_partition(const int* __restrict__ src,
                                                    const int* __restrict__ dst,
                                                    const int* __restrict__ Hist,
                                                    int* __restrict__ srcS,
                                                    int* __restrict__ dstS, int ne) {
    __shared__ int cur[NBKT_PAD];
    for (int i = threadIdx.x; i < NBKT_PAD; i += 256)
        cur[i] = Hist[(size_t)blockIdx.x * NBKT_PAD + i];
    __syncthreads();
    int base = blockIdx.x * CHUNK;
    int lim = min(CHUNK, ne - base);
    for (int i = threadIdx.x; i < lim; i += 256) {
        int d = dst[base + i];
        int s = src[base + i];
        int pos = atomicAdd(&cur[d >> BKT_SHIFT], 1);
        srcS[pos] = s;
        dstS[pos] = d;
    }
}

// ---- K4: per-bucket fine CSR (counting sort over 128 nodes) + row_ptr + dinv ----
__global__ __launch_bounds__(256) void k4_csr(const int* __restrict__ srcS,
                                              const int* __restrict__ dstS,
                                              const int* __restrict__ bktBase,
                                              int* __restrict__ col_idx,
                                              int* __restrict__ row_ptr,
                                              float* __restrict__ dinv, int n) {
    __shared__ int hist[128];
    __shared__ int rbase[128];
    __shared__ int cur[128];
    __shared__ int stage[MAXSEG];
    int b = blockIdx.x;
    int segs = bktBase[b], sege = bktBase[b + 1];
    int seglen = sege - segs;
    int node0 = b << BKT_SHIFT;
    int nloc = min(128, n - node0);
    int t = threadIdx.x;
    if (t < 128) hist[t] = 0;
    __syncthreads();
    for (int i = t; i < seglen; i += 256)
        atomicAdd(&hist[dstS[segs + i] - node0], 1);
    __syncthreads();
    if (t < 64) {  // wave 0: exclusive scan of 128 counters, 2 per lane
        int a0 = hist[2 * t], a1 = hist[2 * t + 1];
        int pair = a0 + a1;
        int x = pair;
        #pragma unroll
        for (int off = 1; off < 64; off <<= 1) {
            int y = __shfl_up(x, off, 64);
            if (t >= off) x += y;
        }
        int excl = x - pair;
        rbase[2 * t] = excl;       rbase[2 * t + 1] = excl + a0;
        cur[2 * t]   = excl;       cur[2 * t + 1]   = excl + a0;
    }
    __syncthreads();
    if (seglen <= MAXSEG) {
        for (int i = t; i < seglen; i += 256) {
            int d = dstS[segs + i] - node0;
            int pos = atomicAdd(&cur[d], 1);
            stage[pos] = srcS[segs + i];
        }
        __syncthreads();
        for (int i = t; i < seglen; i += 256)
            col_idx[segs + i] = stage[i];
    } else {  // overflow fallback: direct (rare with uniform graphs)
        for (int i = t; i < seglen; i += 256) {
            int d = dstS[segs + i] - node0;
            int pos = atomicAdd(&cur[d], 1);
            col_idx[segs + pos] = srcS[segs + i];
        }
    }
    if (t < nloc) {
        row_ptr[node0 + t] = segs + rbase[t];
        dinv[node0 + t] = 1.0f / sqrtf((float)(hist[t] + 1));  // deg incl self loop
    }
}

// ---------------- row-tiled dense GEMM: Y = X @ W ----------------
// Block stages W (K*FOUT) + an RT-row X tile in LDS once, computes RT*FOUT outputs.
// EPI: 0 -> *dinv[row], 1 -> tanh(+bias).
// Pow2 FOUT (32/64/256): col = tid%FOUT, group = tid/FOUT owns RPT rows; k-outer
// loop reuses the W value across RPT row-accumulators, X reads are wave-uniform
// LDS broadcasts. Other FOUT: generic output-per-thread mapping.
template<int K, int FOUT, int EPI, int RT>
__global__ __launch_bounds__(256) void gemm_tiled(const float* __restrict__ X,
        const float* __restrict__ W, const float* __restrict__ bias,
        const float* __restrict__ dinv, float* __restrict__ Y, int nrows) {
    __shared__ float Wl[K * FOUT];
    __shared__ float Xs[RT * K];
    int tid = threadIdx.x;
    const float4* Wg4 = (const float4*)W;
    float4* Wl4 = (float4*)Wl;
    for (int i = tid; i < K * FOUT / 4; i += 256) Wl4[i] = Wg4[i];
    int row0 = blockIdx.x * RT;
    int nr = min(RT, nrows - row0);
    if constexpr ((K & 3) == 0) {
        const float4* Xg4 = (const float4*)(X + (size_t)row0 * K);
        float4* Xs4 = (float4*)Xs;
        int lim = nr * (K / 4);
        for (int i = tid; i < lim; i += 256) Xs4[i] = Xg4[i];
    } else {
        const float* Xg = X + (size_t)row0 * K;
        int lim = nr * K;
        for (int i = tid; i < lim; i += 256) Xs[i] = Xg[i];
    }
    __syncthreads();

    if constexpr (FOUT == 256 || FOUT == 64 || FOUT == 32) {
        constexpr int NG  = 256 / FOUT;   // groups per block
        constexpr int RPT = RT / NG;      // rows per thread
        int c = tid & (FOUT - 1);
        int g = tid / FOUT;
        int rbase = g * RPT;
        float acc[RPT];
        #pragma unroll
        for (int i = 0; i < RPT; ++i) acc[i] = 0.f;
        #pragma unroll 4
        for (int k = 0; k < K; ++k) {
            float wv = Wl[k * FOUT + c];
            #pragma unroll
            for (int i = 0; i < RPT; ++i)
                acc[i] = fmaf(Xs[(rbase + i) * K + k], wv, acc[i]);
        }
        float bv = (EPI == 1) ? bias[c] : 0.f;
        #pragma unroll
        for (int i = 0; i < RPT; ++i) {
            int r = row0 + rbase + i;
            if (r < nrows) {
                float v = acc[i];
                if (EPI == 0) v *= dinv[r];
                else          v = tanhf(v + bv);
                Y[(size_t)r * FOUT + c] = v;
            }
        }
    } else {
        constexpr int TOT = RT * FOUT;
        for (int o = tid; o < TOT; o += 256) {
            int r = o / FOUT;
            int c = o - r * FOUT;
            if (r >= nr) break;
            float acc = 0.f;
            #pragma unroll 4
            for (int k = 0; k < K; ++k)
                acc = fmaf(Xs[r * K + k], Wl[k * FOUT + c], acc);
            int rg = row0 + r;
            float v;
            if (EPI == 0) v = acc * dinv[rg];
            else          v = tanhf(acc + bias[c]);
            Y[(size_t)rg * FOUT + c] = v;
        }
    }
}

// ---------------- CSR aggregation (vectorized) ----------------
template<int F, bool FINAL>
__global__ __launch_bounds__(256) void aggregate_kernel(const float* __restrict__ Z,
        const int* __restrict__ row_ptr, const int* __restrict__ col_idx,
        const float* __restrict__ dinv, const float* __restrict__ bias,
        float* __restrict__ out, int n) {
    constexpr int LPR = F / 4;      // lanes per neighbor row (16 or 8)
    constexpr int G   = 64 / LPR;   // neighbors per step (4 or 8)
    int tid = threadIdx.x;
    int wave = tid >> 6, lane = tid & 63;
    int g = lane / LPR;
    int c = lane - g * LPR;
    int node = blockIdx.x * 4 + wave;
    if (node >= n) return;
    int start = row_ptr[node];
    int end   = row_ptr[node + 1];
    float4 acc = make_float4(0.f, 0.f, 0.f, 0.f);
    int wbase = start;
    int iv = (wbase + lane < end) ? col_idx[wbase + lane] : 0;
    #pragma unroll 2
    for (int base = start; base < end; base += G) {
        if (base - wbase == 64) {
            wbase += 64;
            iv = (wbase + lane < end) ? col_idx[wbase + lane] : 0;
        }
        int s = __shfl(iv, (base - wbase) + g, 64);
        if (base + g < end) {
            const float4 v = *(const float4*)(Z + (size_t)s * F + c * 4);
            acc.x += v.x; acc.y += v.y; acc.z += v.z; acc.w += v.w;
        }
    }
    #pragma unroll
    for (int off = LPR; off < 64; off <<= 1) {
        acc.x += __shfl_xor(acc.x, off, 64);
        acc.y += __shfl_xor(acc.y, off, 64);
        acc.z += __shfl_xor(acc.z, off, 64);
        acc.w += __shfl_xor(acc.w, off, 64);
    }
    if (g == 0) {
        const float4 sv = *(const float4*)(Z + (size_t)node * F + c * 4);
        float di = dinv[node];
        float4 r;
        r.x = di * (acc.x + sv.x);
        r.y = di * (acc.y + sv.y);
        r.z = di * (acc.z + sv.z);
        r.w = di * (acc.w + sv.w);
        if (FINAL) {
            const float4 bv = *(const float4*)(bias + c * 4);
            r.x = tanhf(r.x + bv.x);
            r.y = tanhf(r.y + bv.y);
            r.z = tanhf(r.z + bv.z);
            r.w = tanhf(r.w + bv.w);
        }
        *(float4*)(out + (size_t)node * F + c * 4) = r;
    }
}

__global__ __launch_bounds__(256) void mul_dinv_kernel(const float* __restrict__ h,
        const float* __restrict__ dinv, float* __restrict__ Z, int total, int shift) {
    int idx = blockIdx.x * 256 + threadIdx.x;
    if (idx < total) Z[idx] = h[idx] * dinv[idx >> shift];
}

// ---------------- final: e = [h[src], h[dst]], out = e @ Wc + bc ----------------
__global__ __launch_bounds__(256) void edge_kernel(const int* __restrict__ src,
        const int* __restrict__ dst, const float* __restrict__ h,
        const float* __restrict__ Wc, const float* __restrict__ bc,
        float* __restrict__ out, float* __restrict__ efeat, int ne) {
    __shared__ float Wl[144];
    __shared__ float bl[6];
    if (threadIdx.x < 144) Wl[threadIdx.x] = Wc[threadIdx.x];
    if (threadIdx.x < 6) bl[threadIdx.x] = bc[threadIdx.x];
    __syncthreads();
    int e = blockIdx.x * 256 + threadIdx.x;
    if (e >= ne) return;
    int s = src[e], d = dst[e];
    const float4* hs4 = (const float4*)(h + (size_t)s * 12);
    const float4* hd4 = (const float4*)(h + (size_t)d * 12);
    float4 v0 = hs4[0], v1 = hs4[1], v2 = hs4[2];
    float4 v3 = hd4[0], v4 = hd4[1], v5 = hd4[2];
    float v[24];
    ((float4*)v)[0] = v0; ((float4*)v)[1] = v1; ((float4*)v)[2] = v2;
    ((float4*)v)[3] = v3; ((float4*)v)[4] = v4; ((float4*)v)[5] = v5;
    float4* ef4 = (float4*)(efeat + (size_t)e * 24);
    ef4[0] = v0; ef4[1] = v1; ef4[2] = v2; ef4[3] = v3; ef4[4] = v4; ef4[5] = v5;
    float o[6];
    #pragma unroll
    for (int c = 0; c < 6; ++c) {
        float acc = bl[c];
        #pragma unroll
        for (int k = 0; k < 24; ++k) acc = fmaf(v[k], Wl[k * 6 + c], acc);
        o[c] = acc;
    }
    float2* o2 = (float2*)(out + (size_t)e * 6);
    o2[0] = make_float2(o[0], o[1]);
    o2[1] = make_float2(o[2], o[3]);
    o2[2] = make_float2(o[4], o[5]);
}

extern "C" void kernel_launch(void* const* d_in, const int* in_sizes, int n_in,
                              void* d_out, int out_size, void* d_ws, size_t ws_size,
                              hipStream_t stream) {
    const int N = in_sizes[0] / 128;
    const int E = in_sizes[1] / 2;

    const float* x   = (const float*)d_in[0];
    const int*   ei  = (const int*)d_in[1];
    const int*   srcE = ei;
    const int*   dstE = ei + E;
    const float* W1 = (const float*)d_in[3];  const float* b1 = (const float*)d_in[4];
    const float* W2 = (const float*)d_in[5];  const float* b2 = (const float*)d_in[6];
    const float* W3 = (const float*)d_in[7];  const float* b3 = (const float*)d_in[8];
    const float* W4 = (const float*)d_in[9];  const float* b4 = (const float*)d_in[10];
    const float* W5 = (const float*)d_in[11]; const float* b5 = (const float*)d_in[12];
    const float* Wl1 = (const float*)d_in[13]; const float* bl1 = (const float*)d_in[14];
    const float* Wl2 = (const float*)d_in[15]; const float* bl2 = (const float*)d_in[16];
    const float* Wl3 = (const float*)d_in[17]; const float* bl3 = (const float*)d_in[18];
    const float* Wc  = (const float*)d_in[19]; const float* bc  = (const float*)d_in[20];

    // ---- workspace (small persistent arrays) ----
    char* ws = (char*)d_ws;
    size_t off = 0;
    auto take = [&](size_t bytes) -> char* {
        char* p = ws + off;
        off += (bytes + 255) & ~(size_t)255;
        return p;
    };
    int*   row_ptr = (int*)take((size_t)(N + 1) * 4);
    float* dinv    = (float*)take((size_t)N * 4);
    int*   col_idx = (int*)take((size_t)E * 4);
    float* h8      = (float*)take((size_t)N * 12 * 4);
    int*   bktBase = (int*)take((size_t)(NBKT_PAD + 1) * 4);

    // big/transient buffers inside d_out's e-region (dead until edge_kernel overwrites it)
    float* outbuf  = (float*)d_out;
    float* eregion = outbuf + (size_t)E * 6;
    int* srcS = (int*)eregion;
    int* dstS = srcS + E;
    int* Hist = dstS + E;
    float* bufZ = eregion;                       // up to N*64
    float* bufH = eregion + (size_t)N * 64;      // up to N*64
    float* bufC = eregion + (size_t)N * 128;     // N*256 (h5)

    int gE = (E + 255) / 256;
    int gAgg = (N + 3) / 4;
    int nblk = (E + CHUNK - 1) / CHUNK;
    int nbkt = (N + 127) >> BKT_SHIFT;
    auto tiles = [&](int rt) { return (N + rt - 1) / rt; };

    // ---- CSR build (no global atomics) ----
    k1_hist<<<nblk, 256, 0, stream>>>(dstE, Hist, E);
    k2_scan<<<1, 1024, 0, stream>>>(Hist, bktBase, row_ptr + N, nblk);
    k3_partition<<<nblk, 256, 0, stream>>>(srcE, dstE, Hist, srcS, dstS, E);
    k4_csr<<<nbkt, 256, 0, stream>>>(srcS, dstS, bktBase, col_idx, row_ptr, dinv, N);

    // ---- layer 1: 128 -> 64 ----
    gemm_tiled<128, 64, 0, 16><<<tiles(16), 256, 0, stream>>>(x, W1, nullptr, dinv, bufZ, N);
    aggregate_kernel<64, true><<<gAgg, 256, 0, stream>>>(bufZ, row_ptr, col_idx, dinv, b1, bufH, N);
    // ---- layer 2: 64 -> 64 ----
    gemm_tiled<64, 64, 0, 16><<<tiles(16), 256, 0, stream>>>(bufH, W2, nullptr, dinv, bufZ, N);
    aggregate_kernel<64, true><<<gAgg, 256, 0, stream>>>(bufZ, row_ptr, col_idx, dinv, b2, bufH, N);
    // ---- layer 3: 64 -> 32 ----
    gemm_tiled<64, 32, 0, 16><<<tiles(16), 256, 0, stream>>>(bufH, W3, nullptr, dinv, bufZ, N);
    aggregate_kernel<32, true><<<gAgg, 256, 0, stream>>>(bufZ, row_ptr, col_idx, dinv, b3, bufH, N);
    // ---- layer 4: 32 -> 32 ----
    gemm_tiled<32, 32, 0, 16><<<tiles(16), 256, 0, stream>>>(bufH, W4, nullptr, dinv, bufZ, N);
    aggregate_kernel<32, true><<<gAgg, 256, 0, stream>>>(bufZ, row_ptr, col_idx, dinv, b4, bufH, N);
    // ---- layer 5: aggregate first (32 wide), then 32 -> 256 GEMM ----
    mul_dinv_kernel<<<(N * 32 + 255) / 256, 256, 0, stream>>>(bufH, dinv, bufZ, N * 32, 5);
    aggregate_kernel<32, false><<<gAgg, 256, 0, stream>>>(bufZ, row_ptr, col_idx, dinv, nullptr, bufH, N);
    gemm_tiled<32, 256, 1, 16><<<tiles(16), 256, 0, stream>>>(bufH, W5, b5, nullptr, bufC, N);
    // ---- linear layers ----
    gemm_tiled<256, 24, 1, 16><<<tiles(16), 256, 0, stream>>>(bufC, Wl1, bl1, nullptr, bufZ, N);
    gemm_tiled<24, 18, 1, 64><<<tiles(64), 256, 0, stream>>>(bufZ, Wl2, bl2, nullptr, bufH, N);
    gemm_tiled<18, 12, 1, 64><<<tiles(64), 256, 0, stream>>>(bufH, Wl3, bl3, nullptr, h8, N);
    // ---- edge output ----
    edge_kernel<<<gE, 256, 0, stream>>>(srcE, dstE, h8, Wc, bc, outbuf, eregion, E);
}